// Round 2
// baseline (1249.713 us; speedup 1.0000x reference)
//
#include <hip/hip_runtime.h>
#include <hip/hip_bf16.h>

#define B_ 4
#define T_ 1024
#define C_ 512
#define H_ 8
#define D_ 64

// ---------------------------------------------------------------------------
// GEMM 1: QKV projection.  Y = A @ W + bias, A fp32 [4096,512], W fp32 [512,512]
// z=0: Q (scaled by 1/8), z=1: K, z=2: V.  Output fp32 to workspace.
// Tile 64x64, K-chunk 16, block 256 (each thread 4x4).
// ---------------------------------------------------------------------------
__global__ __launch_bounds__(256) void qkv_gemm(
    const float* __restrict__ x, const float* __restrict__ cc,
    const float* __restrict__ Wq, const float* __restrict__ bq,
    const float* __restrict__ Wk, const float* __restrict__ bk,
    const float* __restrict__ Wv, const float* __restrict__ bv,
    float* __restrict__ Qo, float* __restrict__ Ko, float* __restrict__ Vo)
{
    const int z = blockIdx.z;
    const float* A    = (z == 0) ? x  : cc;
    const float* W    = (z == 0) ? Wq : (z == 1 ? Wk : Wv);
    const float* bias = (z == 0) ? bq : (z == 1 ? bk : bv);
    float* Y          = (z == 0) ? Qo : (z == 1 ? Ko : Vo);
    const float scale = (z == 0) ? 0.125f : 1.0f;

    __shared__ __align__(16) float sA[16][64];  // sA[k][m]
    __shared__ __align__(16) float sB[16][64];  // sB[k][n]

    const int tid = threadIdx.x;
    const int m0 = blockIdx.y * 64;
    const int n0 = blockIdx.x * 64;
    const int ty = tid >> 4, tx = tid & 15;

    float acc[4][4] = {};

    const int mmL = tid >> 2;           // 0..63
    const int kkL = (tid & 3) * 4;      // 0,4,8,12
    const int kkB = tid >> 4;           // 0..15
    const int nnB = (tid & 15) * 4;     // 0..60

    for (int kc = 0; kc < 512; kc += 16) {
        const float4 av = *(const float4*)&A[(size_t)(m0 + mmL) * 512 + kc + kkL];
        sA[kkL + 0][mmL] = av.x;
        sA[kkL + 1][mmL] = av.y;
        sA[kkL + 2][mmL] = av.z;
        sA[kkL + 3][mmL] = av.w;
        const float4 wv = *(const float4*)&W[(size_t)(kc + kkB) * 512 + n0 + nnB];
        *(float4*)&sB[kkB][nnB] = wv;
        __syncthreads();
        #pragma unroll
        for (int kk = 0; kk < 16; kk++) {
            const float4 a4 = *(const float4*)&sA[kk][ty * 4];
            const float4 b4 = *(const float4*)&sB[kk][tx * 4];
            const float a[4] = {a4.x, a4.y, a4.z, a4.w};
            const float b[4] = {b4.x, b4.y, b4.z, b4.w};
            #pragma unroll
            for (int i = 0; i < 4; i++)
                #pragma unroll
                for (int j = 0; j < 4; j++)
                    acc[i][j] = fmaf(a[i], b[j], acc[i][j]);
        }
        __syncthreads();
    }

    #pragma unroll
    for (int i = 0; i < 4; i++) {
        const int m = m0 + ty * 4 + i;
        const int n = n0 + tx * 4;
        float4 o;
        o.x = (acc[i][0] + bias[n + 0]) * scale;
        o.y = (acc[i][1] + bias[n + 1]) * scale;
        o.z = (acc[i][2] + bias[n + 2]) * scale;
        o.w = (acc[i][3] + bias[n + 3]) * scale;
        *(float4*)&Y[(size_t)m * 512 + n] = o;
    }
}

// ---------------------------------------------------------------------------
// GEMM 2: output projection.  out = AO @ Wo + bo.  All fp32.
// ---------------------------------------------------------------------------
__global__ __launch_bounds__(256) void out_gemm(
    const float* __restrict__ A, const float* __restrict__ W,
    const float* __restrict__ bias, float* __restrict__ Y)
{
    __shared__ __align__(16) float sA[16][64];
    __shared__ __align__(16) float sB[16][64];

    const int tid = threadIdx.x;
    const int m0 = blockIdx.y * 64;
    const int n0 = blockIdx.x * 64;
    const int ty = tid >> 4, tx = tid & 15;

    float acc[4][4] = {};

    const int mmL = tid >> 2;
    const int kkL = (tid & 3) * 4;
    const int kkB = tid >> 4;
    const int nnB = (tid & 15) * 4;

    for (int kc = 0; kc < 512; kc += 16) {
        const float4 av = *(const float4*)&A[(size_t)(m0 + mmL) * 512 + kc + kkL];
        sA[kkL + 0][mmL] = av.x;
        sA[kkL + 1][mmL] = av.y;
        sA[kkL + 2][mmL] = av.z;
        sA[kkL + 3][mmL] = av.w;
        const float4 wv = *(const float4*)&W[(size_t)(kc + kkB) * 512 + n0 + nnB];
        *(float4*)&sB[kkB][nnB] = wv;
        __syncthreads();
        #pragma unroll
        for (int kk = 0; kk < 16; kk++) {
            const float4 a4 = *(const float4*)&sA[kk][ty * 4];
            const float4 b4 = *(const float4*)&sB[kk][tx * 4];
            const float a[4] = {a4.x, a4.y, a4.z, a4.w};
            const float b[4] = {b4.x, b4.y, b4.z, b4.w};
            #pragma unroll
            for (int i = 0; i < 4; i++)
                #pragma unroll
                for (int j = 0; j < 4; j++)
                    acc[i][j] = fmaf(a[i], b[j], acc[i][j]);
        }
        __syncthreads();
    }

    #pragma unroll
    for (int i = 0; i < 4; i++) {
        const int m = m0 + ty * 4 + i;
        const int n = n0 + tx * 4;
        float4 o;
        o.x = acc[i][0] + bias[n + 0];
        o.y = acc[i][1] + bias[n + 1];
        o.z = acc[i][2] + bias[n + 2];
        o.w = acc[i][3] + bias[n + 3];
        *(float4*)&Y[(size_t)m * 512 + n] = o;
    }
}

// ---------------------------------------------------------------------------
// Flash-style attention with relative-position band bias.
// Block = 256 threads (4 waves), each wave owns 8 q-rows, block owns 32 rows
// of one (b,h).  Grid (T/32, H, B).  lane <-> d (D=64 = wave width).
// Q in ws is pre-scaled by 1/8.
// ---------------------------------------------------------------------------
__global__ __launch_bounds__(256) void attn_kernel(
    const float* __restrict__ Q, const float* __restrict__ K,
    const float* __restrict__ V,
    const float* __restrict__ rk, const float* __restrict__ rv,
    float* __restrict__ AO)
{
    __shared__ __align__(16) float qs[32 * 64];      // q rows (scaled)
    __shared__ __align__(16) float qb[32 * 9];       // band bias dots
    __shared__ __align__(16) float Kt[64 * 65];      // TRANSPOSED: Kt[d*65 + s]
    __shared__ __align__(16) float Vt[64 * 65];      // row-major: Vt[s*65 + d]
    __shared__ __align__(16) float pb[32 * 64];      // p values per row

    const int b = blockIdx.z, h = blockIdx.y, tb = blockIdx.x;
    const int t0 = tb * 32;
    const int tid = threadIdx.x;
    const int wave = tid >> 6, lane = tid & 63;
    const int r0 = wave * 8;

    const size_t base = ((size_t)b * T_) * C_ + (size_t)h * D_;

    // stage q rows
    for (int idx = tid; idx < 32 * 64; idx += 256) {
        const int r = idx >> 6, d = idx & 63;
        qs[idx] = Q[base + (size_t)(t0 + r) * C_ + d];
    }
    __syncthreads();
    // band bias dots: qb[r][w] = q_r . rel_k[w]
    for (int idx = tid; idx < 32 * 9; idx += 256) {
        const int r = idx / 9, w = idx - r * 9;
        float s = 0.f;
        for (int d = 0; d < 64; d++) s = fmaf(qs[r * 64 + d], rk[w * 64 + d], s);
        qb[idx] = s;
    }
    // (visibility of qb covered by the syncthreads at top of the chunk loop)

    float m8[8], l8[8], oacc[8], resc8[8];
    #pragma unroll
    for (int r = 0; r < 8; r++) { m8[r] = -1e30f; l8[r] = 0.f; oacc[r] = 0.f; }

    for (int scnk = 0; scnk < 16; scnk++) {
        const int s0 = scnk * 64;
        __syncthreads();
        for (int idx = tid; idx < 64 * 64; idx += 256) {
            const int i = idx >> 6, d = idx & 63;
            const size_t g = base + (size_t)(s0 + i) * C_ + d;
            Kt[d * 65 + i] = K[g];
            Vt[i * 65 + d] = V[g];
        }
        __syncthreads();

        // scores: lane j holds score(t=r, s=s0+j) for this wave's 8 rows
        float sc8[8] = {0.f, 0.f, 0.f, 0.f, 0.f, 0.f, 0.f, 0.f};
        #pragma unroll
        for (int d4 = 0; d4 < 16; d4++) {
            const float k0 = Kt[(d4 * 4 + 0) * 65 + lane];
            const float k1 = Kt[(d4 * 4 + 1) * 65 + lane];
            const float k2 = Kt[(d4 * 4 + 2) * 65 + lane];
            const float k3 = Kt[(d4 * 4 + 3) * 65 + lane];
            #pragma unroll
            for (int r = 0; r < 8; r++) {
                const float4 q4 = *(const float4*)&qs[(r0 + r) * 64 + d4 * 4];
                sc8[r] = fmaf(k0, q4.x, fmaf(k1, q4.y, fmaf(k2, q4.z, fmaf(k3, q4.w, sc8[r]))));
            }
        }
        // online softmax per row
        #pragma unroll
        for (int rr = 0; rr < 8; rr++) {
            const int t = t0 + r0 + rr;
            float score = sc8[rr];
            const int rel = s0 + lane - t;
            if (rel >= -4 && rel <= 4) score += qb[(r0 + rr) * 9 + rel + 4];
            float cmax = score;
            #pragma unroll
            for (int off = 32; off > 0; off >>= 1)
                cmax = fmaxf(cmax, __shfl_xor(cmax, off, 64));
            const float mnew = fmaxf(m8[rr], cmax);
            const float p = __expf(score - mnew);
            resc8[rr] = __expf(m8[rr] - mnew);
            float psum = p;
            #pragma unroll
            for (int off = 32; off > 0; off >>= 1)
                psum += __shfl_xor(psum, off, 64);
            l8[rr] = l8[rr] * resc8[rr] + psum;
            m8[rr] = mnew;
            oacc[rr] *= resc8[rr];
            pb[(r0 + rr) * 64 + lane] = p;
        }
        // PV: lane <-> d, p broadcast from LDS (same-wave region, in-order DS)
        #pragma unroll
        for (int j4 = 0; j4 < 16; j4++) {
            const float v0 = Vt[(j4 * 4 + 0) * 65 + lane];
            const float v1 = Vt[(j4 * 4 + 1) * 65 + lane];
            const float v2 = Vt[(j4 * 4 + 2) * 65 + lane];
            const float v3 = Vt[(j4 * 4 + 3) * 65 + lane];
            #pragma unroll
            for (int rr = 0; rr < 8; rr++) {
                const float4 p4 = *(const float4*)&pb[(r0 + rr) * 64 + j4 * 4];
                oacc[rr] = fmaf(v0, p4.x, fmaf(v1, p4.y, fmaf(v2, p4.z, fmaf(v3, p4.w, oacc[rr]))));
            }
        }
    }

    // epilogue: band rel-v term (recompute band p from final m,l) + normalize
    for (int rr = 0; rr < 8; rr++) {
        const int t = t0 + r0 + rr;
        float o = oacc[rr];
        #pragma unroll
        for (int w = 0; w < 9; w++) {
            const int s = t + w - 4;
            if (s < 0 || s >= T_) continue;
            float part = qs[(r0 + rr) * 64 + lane] * K[base + (size_t)s * C_ + lane];
            #pragma unroll
            for (int off = 32; off > 0; off >>= 1)
                part += __shfl_xor(part, off, 64);
            const float p = __expf(part + qb[(r0 + rr) * 9 + w] - m8[rr]);
            o = fmaf(p, rv[w * 64 + lane], o);
        }
        AO[base + (size_t)t * C_ + lane] = o / l8[rr];
    }
}

// ---------------------------------------------------------------------------
extern "C" void kernel_launch(void* const* d_in, const int* in_sizes, int n_in,
                              void* d_out, int out_size, void* d_ws, size_t ws_size,
                              hipStream_t stream)
{
    const float* x  = (const float*)d_in[0];
    const float* c  = (const float*)d_in[1];
    const float* Wq = (const float*)d_in[2];
    const float* bq = (const float*)d_in[3];
    const float* Wk = (const float*)d_in[4];
    const float* bk = (const float*)d_in[5];
    const float* Wv = (const float*)d_in[6];
    const float* bv = (const float*)d_in[7];
    const float* Wo = (const float*)d_in[8];
    const float* bo = (const float*)d_in[9];
    const float* rk = (const float*)d_in[10];
    const float* rv = (const float*)d_in[11];

    float* Q  = (float*)d_ws;                    // 4096x512 fp32, pre-scaled 1/8
    float* K  = Q + (size_t)4096 * 512;
    float* V  = K + (size_t)4096 * 512;
    float* AO = V + (size_t)4096 * 512;          // total ws use: 32 MB

    qkv_gemm<<<dim3(8, 64, 3), 256, 0, stream>>>(x, c, Wq, bq, Wk, bk, Wv, bv, Q, K, V);
    attn_kernel<<<dim3(32, 8, 4), 256, 0, stream>>>(Q, K, V, rk, rv, AO);
    out_gemm<<<dim3(8, 64, 1), 256, 0, stream>>>(AO, Wo, bo, (float*)d_out);
}

// Round 3
// 283.406 us; speedup vs baseline: 4.4096x; 4.4096x over previous
//
#include <hip/hip_runtime.h>
#include <hip/hip_bf16.h>

#define B_ 4
#define T_ 1024
#define C_ 512
#define H_ 8

typedef __attribute__((ext_vector_type(8))) short short8;
typedef __attribute__((ext_vector_type(4))) float floatx4;

__device__ __forceinline__ unsigned short f2bs(float f) {
    __hip_bfloat16 h = __float2bfloat16(f);
    return *(unsigned short*)&h;
}
__device__ __forceinline__ float bs2f(unsigned short u) {
    __hip_bfloat16 h;
    *(unsigned short*)&h = u;
    return __bfloat162float(h);
}

// ---------------------------------------------------------------------------
// QKV projection: Y = A @ W + bias (fp32 in), emitted as bf16 in per-head
// compact layout [bh][t][64].  z=0: Q (pre-scaled 1/8), z=1: K, z=2: V.
// n-tile (blockIdx.x) of 64 == exactly one head.
// ---------------------------------------------------------------------------
__global__ __launch_bounds__(256) void qkv_gemm(
    const float* __restrict__ x, const float* __restrict__ cc,
    const float* __restrict__ Wq, const float* __restrict__ bq,
    const float* __restrict__ Wk, const float* __restrict__ bk,
    const float* __restrict__ Wv, const float* __restrict__ bv,
    unsigned short* __restrict__ Qo, unsigned short* __restrict__ Ko,
    unsigned short* __restrict__ Vo)
{
    const int z = blockIdx.z;
    const float* A    = (z == 0) ? x  : cc;
    const float* W    = (z == 0) ? Wq : (z == 1 ? Wk : Wv);
    const float* bias = (z == 0) ? bq : (z == 1 ? bk : bv);
    unsigned short* Y = (z == 0) ? Qo : (z == 1 ? Ko : Vo);
    const float scale = (z == 0) ? 0.125f : 1.0f;

    __shared__ __align__(16) float sA[16][64];  // sA[k][m]
    __shared__ __align__(16) float sB[16][64];  // sB[k][n]

    const int tid = threadIdx.x;
    const int m0 = blockIdx.y * 64;
    const int n0 = blockIdx.x * 64;
    const int ty = tid >> 4, tx = tid & 15;

    float acc[4][4] = {};

    const int mmL = tid >> 2;           // 0..63
    const int kkL = (tid & 3) * 4;      // 0,4,8,12
    const int kkB = tid >> 4;           // 0..15
    const int nnB = (tid & 15) * 4;     // 0..60

    for (int kc = 0; kc < 512; kc += 16) {
        const float4 av = *(const float4*)&A[(size_t)(m0 + mmL) * 512 + kc + kkL];
        sA[kkL + 0][mmL] = av.x;
        sA[kkL + 1][mmL] = av.y;
        sA[kkL + 2][mmL] = av.z;
        sA[kkL + 3][mmL] = av.w;
        const float4 wv = *(const float4*)&W[(size_t)(kc + kkB) * 512 + n0 + nnB];
        *(float4*)&sB[kkB][nnB] = wv;
        __syncthreads();
        #pragma unroll
        for (int kk = 0; kk < 16; kk++) {
            const float4 a4 = *(const float4*)&sA[kk][ty * 4];
            const float4 b4 = *(const float4*)&sB[kk][tx * 4];
            const float a[4] = {a4.x, a4.y, a4.z, a4.w};
            const float b[4] = {b4.x, b4.y, b4.z, b4.w};
            #pragma unroll
            for (int i = 0; i < 4; i++)
                #pragma unroll
                for (int j = 0; j < 4; j++)
                    acc[i][j] = fmaf(a[i], b[j], acc[i][j]);
        }
        __syncthreads();
    }

    const int h = blockIdx.x;           // head == n-tile
    #pragma unroll
    for (int i = 0; i < 4; i++) {
        const int m = m0 + ty * 4 + i;
        const int bb = m >> 10, t = m & 1023;
        const size_t obase = (((size_t)bb * H_ + h) * T_ + t) * 64 + tx * 4;
        #pragma unroll
        for (int j = 0; j < 4; j++) {
            const int n = n0 + tx * 4 + j;
            Y[obase + j] = f2bs((acc[i][j] + bias[n]) * scale);
        }
    }
}

// ---------------------------------------------------------------------------
// Output projection: out = AO @ Wo + bo.  All fp32.
// ---------------------------------------------------------------------------
__global__ __launch_bounds__(256) void out_gemm(
    const float* __restrict__ A, const float* __restrict__ W,
    const float* __restrict__ bias, float* __restrict__ Y)
{
    __shared__ __align__(16) float sA[16][64];
    __shared__ __align__(16) float sB[16][64];

    const int tid = threadIdx.x;
    const int m0 = blockIdx.y * 64;
    const int n0 = blockIdx.x * 64;
    const int ty = tid >> 4, tx = tid & 15;

    float acc[4][4] = {};

    const int mmL = tid >> 2;
    const int kkL = (tid & 3) * 4;
    const int kkB = tid >> 4;
    const int nnB = (tid & 15) * 4;

    for (int kc = 0; kc < 512; kc += 16) {
        const float4 av = *(const float4*)&A[(size_t)(m0 + mmL) * 512 + kc + kkL];
        sA[kkL + 0][mmL] = av.x;
        sA[kkL + 1][mmL] = av.y;
        sA[kkL + 2][mmL] = av.z;
        sA[kkL + 3][mmL] = av.w;
        const float4 wv = *(const float4*)&W[(size_t)(kc + kkB) * 512 + n0 + nnB];
        *(float4*)&sB[kkB][nnB] = wv;
        __syncthreads();
        #pragma unroll
        for (int kk = 0; kk < 16; kk++) {
            const float4 a4 = *(const float4*)&sA[kk][ty * 4];
            const float4 b4 = *(const float4*)&sB[kk][tx * 4];
            const float a[4] = {a4.x, a4.y, a4.z, a4.w};
            const float b[4] = {b4.x, b4.y, b4.z, b4.w};
            #pragma unroll
            for (int i = 0; i < 4; i++)
                #pragma unroll
                for (int j = 0; j < 4; j++)
                    acc[i][j] = fmaf(a[i], b[j], acc[i][j]);
        }
        __syncthreads();
    }

    #pragma unroll
    for (int i = 0; i < 4; i++) {
        const int m = m0 + ty * 4 + i;
        const int n = n0 + tx * 4;
        float4 o;
        o.x = acc[i][0] + bias[n + 0];
        o.y = acc[i][1] + bias[n + 1];
        o.z = acc[i][2] + bias[n + 2];
        o.w = acc[i][3] + bias[n + 3];
        *(float4*)&Y[(size_t)m * 512 + n] = o;
    }
}

// ---------------------------------------------------------------------------
// MFMA flash attention.  Block = 4 waves; wave w owns q-rows [t0+16w, t0+16w+16).
// Grid (T/64, H, B).  bf16 16x16x32 MFMA; fragments:
//   A/B: m(or n)=lane&15, k=(lane>>4)*8+j;  C/D: col=lane&15, row=(lane>>4)*4+reg.
// ---------------------------------------------------------------------------
__global__ __launch_bounds__(256) void attn_mfma(
    const unsigned short* __restrict__ Qc, const unsigned short* __restrict__ Kc,
    const unsigned short* __restrict__ Vc,
    const float* __restrict__ rk, const float* __restrict__ rv,
    float* __restrict__ AO)
{
    __shared__ float qbL[64 * 9];                       // q . rel_k per row/window
    __shared__ float bandL[64 * 9];                     // raw band scores (w/ bias)
    __shared__ float rvL[9 * 64];                       // rel_v staged
    __shared__ __align__(16) unsigned short VtL[64 * 72];  // V^T: [d][s], pad 72
    __shared__ __align__(16) float PL[4][16 * 68];      // per-wave P, pad 68

    const int tb = blockIdx.x, h = blockIdx.y, b = blockIdx.z;
    const int bh = b * H_ + h;
    const int tid = threadIdx.x;
    const int wave = tid >> 6, lane = tid & 63;
    const int t0 = tb * 64;
    const int t0w = t0 + wave * 16;
    const size_t qkbase = (size_t)bh * T_ * 64;

    // ---- prologue: band init, rv stage, qb dots (visible after first barrier)
    for (int idx = tid; idx < 576; idx += 256) {
        bandL[idx] = -1e30f;
        rvL[idx] = rv[idx];
        const int row = idx / 9, w = idx - row * 9;
        const unsigned short* qp = &Qc[qkbase + (size_t)(t0 + row) * 64];
        float s = 0.f;
        for (int d = 0; d < 64; d++) s = fmaf(bs2f(qp[d]), rk[w * 64 + d], s);
        qbL[idx] = s;
    }

    const int mrow = lane & 15;
    const int kgrp = (lane >> 4) * 8;

    // Q A-fragments (fixed for the whole kernel)
    const short8 aQ0 = *(const short8*)&Qc[qkbase + (size_t)(t0w + mrow) * 64 + kgrp];
    const short8 aQ1 = *(const short8*)&Qc[qkbase + (size_t)(t0w + mrow) * 64 + 32 + kgrp];

    floatx4 Oc[4];
    float mrun[4], lrun[4];
    #pragma unroll
    for (int r = 0; r < 4; r++) { mrun[r] = -1e30f; lrun[r] = 0.f; }
    #pragma unroll
    for (int dt = 0; dt < 4; dt++) Oc[dt] = (floatx4){0.f, 0.f, 0.f, 0.f};

    float* Pw = &PL[wave][0];
    float* qbw = &qbL[wave * 16 * 9];
    float* bandw = &bandL[wave * 16 * 9];

    for (int ck = 0; ck < 16; ck++) {
        const int s0 = ck * 64;
        __syncthreads();                               // prev chunk's Vt reads done
        // stage V^T chunk [64s x 64d] -> VtL[d][s]
        {
            const int srow = tid >> 3;                 // 0..31
            const int dbase = (tid & 7) * 8;
            #pragma unroll
            for (int pass = 0; pass < 2; pass++) {
                const int s = pass * 32 + srow;
                const short8 vv = *(const short8*)&Vc[qkbase + (size_t)(s0 + s) * 64 + dbase];
                #pragma unroll
                for (int i = 0; i < 8; i++)
                    VtL[(dbase + i) * 72 + s] = (unsigned short)vv[i];
            }
        }
        __syncthreads();

        // ---- S = Q K^T for 4 column tiles of 16
        floatx4 Sc[4];
        #pragma unroll
        for (int st = 0; st < 4; st++) {
            const size_t krow = qkbase + (size_t)(s0 + st * 16 + mrow) * 64;
            const short8 bK0 = *(const short8*)&Kc[krow + kgrp];
            const short8 bK1 = *(const short8*)&Kc[krow + 32 + kgrp];
            floatx4 s4 = {0.f, 0.f, 0.f, 0.f};
            s4 = __builtin_amdgcn_mfma_f32_16x16x32_bf16(aQ0, bK0, s4, 0, 0, 0);
            s4 = __builtin_amdgcn_mfma_f32_16x16x32_bf16(aQ1, bK1, s4, 0, 0, 0);
            Sc[st] = s4;
        }

        // ---- band bias add + raw-score capture
        #pragma unroll
        for (int st = 0; st < 4; st++) {
            #pragma unroll
            for (int r = 0; r < 4; r++) {
                const int tloc = (lane >> 4) * 4 + r;
                const int rel = (s0 + st * 16 + mrow) - (t0w + tloc);
                if (rel >= -4 && rel <= 4) {
                    const float sc = Sc[st][r] + qbw[tloc * 9 + rel + 4];
                    Sc[st][r] = sc;
                    bandw[tloc * 9 + rel + 4] = sc;
                }
            }
        }

        // ---- online softmax over this 64-col chunk
        float resc[4], ls[4];
        #pragma unroll
        for (int r = 0; r < 4; r++) {
            float mc = fmaxf(fmaxf(Sc[0][r], Sc[1][r]), fmaxf(Sc[2][r], Sc[3][r]));
            #pragma unroll
            for (int mk = 1; mk < 16; mk <<= 1)
                mc = fmaxf(mc, __shfl_xor(mc, mk));
            const float mnew = fmaxf(mrun[r], mc);
            resc[r] = __expf(mrun[r] - mnew);
            mrun[r] = mnew;
            ls[r] = 0.f;
        }
        #pragma unroll
        for (int st = 0; st < 4; st++) {
            #pragma unroll
            for (int r = 0; r < 4; r++) {
                const int tloc = (lane >> 4) * 4 + r;
                const float p = __expf(Sc[st][r] - mrun[r]);
                Pw[tloc * 68 + st * 16 + mrow] = p;
                ls[r] += p;
            }
        }
        #pragma unroll
        for (int r = 0; r < 4; r++) {
            float v = ls[r];
            #pragma unroll
            for (int mk = 1; mk < 16; mk <<= 1)
                v += __shfl_xor(v, mk);
            lrun[r] = lrun[r] * resc[r] + v;
        }
        #pragma unroll
        for (int dt = 0; dt < 4; dt++)
            #pragma unroll
            for (int r = 0; r < 4; r++)
                Oc[dt][r] *= resc[r];

        // ---- O += P V   (P via LDS round-trip into A-layout)
        #pragma unroll
        for (int c = 0; c < 2; c++) {
            const float4 p0 = *(const float4*)&Pw[mrow * 68 + c * 32 + kgrp];
            const float4 p1 = *(const float4*)&Pw[mrow * 68 + c * 32 + kgrp + 4];
            short8 aP;
            aP[0] = (short)f2bs(p0.x); aP[1] = (short)f2bs(p0.y);
            aP[2] = (short)f2bs(p0.z); aP[3] = (short)f2bs(p0.w);
            aP[4] = (short)f2bs(p1.x); aP[5] = (short)f2bs(p1.y);
            aP[6] = (short)f2bs(p1.z); aP[7] = (short)f2bs(p1.w);
            #pragma unroll
            for (int dt = 0; dt < 4; dt++) {
                const short8 bV = *(const short8*)&VtL[(dt * 16 + mrow) * 72 + c * 32 + kgrp];
                Oc[dt] = __builtin_amdgcn_mfma_f32_16x16x32_bf16(aP, bV, Oc[dt], 0, 0, 0);
            }
        }
    }

    // ---- epilogue: normalize + band rel-v term
    float invl[4];
    #pragma unroll
    for (int r = 0; r < 4; r++) invl[r] = 1.f / lrun[r];
    #pragma unroll
    for (int dt = 0; dt < 4; dt++)
        #pragma unroll
        for (int r = 0; r < 4; r++)
            Oc[dt][r] *= invl[r];

    for (int w = 0; w < 9; w++) {
        float pw[4];
        #pragma unroll
        for (int r = 0; r < 4; r++) {
            const int tloc = (lane >> 4) * 4 + r;
            pw[r] = __expf(bandw[tloc * 9 + w] - mrun[r]) * invl[r];
        }
        #pragma unroll
        for (int dt = 0; dt < 4; dt++) {
            const float rvv = rvL[w * 64 + dt * 16 + mrow];
            #pragma unroll
            for (int r = 0; r < 4; r++)
                Oc[dt][r] = fmaf(pw[r], rvv, Oc[dt][r]);
        }
    }

    const size_t aobase = ((size_t)b * T_) * C_ + (size_t)h * 64;
    #pragma unroll
    for (int dt = 0; dt < 4; dt++)
        #pragma unroll
        for (int r = 0; r < 4; r++) {
            const int t = t0w + (lane >> 4) * 4 + r;
            AO[aobase + (size_t)t * C_ + dt * 16 + mrow] = Oc[dt][r];
        }
}

// ---------------------------------------------------------------------------
extern "C" void kernel_launch(void* const* d_in, const int* in_sizes, int n_in,
                              void* d_out, int out_size, void* d_ws, size_t ws_size,
                              hipStream_t stream)
{
    const float* x  = (const float*)d_in[0];
    const float* c  = (const float*)d_in[1];
    const float* Wq = (const float*)d_in[2];
    const float* bq = (const float*)d_in[3];
    const float* Wk = (const float*)d_in[4];
    const float* bk = (const float*)d_in[5];
    const float* Wv = (const float*)d_in[6];
    const float* bv = (const float*)d_in[7];
    const float* Wo = (const float*)d_in[8];
    const float* bo = (const float*)d_in[9];
    const float* rk = (const float*)d_in[10];
    const float* rv = (const float*)d_in[11];

    unsigned short* Qc = (unsigned short*)d_ws;           // [32][1024][64] bf16
    unsigned short* Kc = Qc + (size_t)32 * 1024 * 64;
    unsigned short* Vc = Kc + (size_t)32 * 1024 * 64;
    float* AO = (float*)(Vc + (size_t)32 * 1024 * 64);    // [4][1024][512] fp32

    qkv_gemm<<<dim3(8, 64, 3), 256, 0, stream>>>(x, c, Wq, bq, Wk, bk, Wv, bv, Qc, Kc, Vc);
    attn_mfma<<<dim3(16, 8, 4), 256, 0, stream>>>(Qc, Kc, Vc, rk, rv, AO);
    out_gemm<<<dim3(8, 64, 1), 256, 0, stream>>>(AO, Wo, bo, (float*)d_out);
}

// Round 4
// 187.996 us; speedup vs baseline: 6.6475x; 1.5075x over previous
//
#include <hip/hip_runtime.h>
#include <hip/hip_bf16.h>

#define B_ 4
#define T_ 1024
#define C_ 512
#define H_ 8

typedef __attribute__((ext_vector_type(8))) short short8;
typedef __attribute__((ext_vector_type(4))) float floatx4;

__device__ __forceinline__ unsigned short f2bs(float f) {
    __hip_bfloat16 h = __float2bfloat16(f);
    return *(unsigned short*)&h;
}
__device__ __forceinline__ float bs2f(unsigned short u) {
    __hip_bfloat16 h;
    *(unsigned short*)&h = u;
    return __bfloat162float(h);
}

__device__ __forceinline__ void gload_lds16(const void* g, void* l) {
    __builtin_amdgcn_global_load_lds(
        (const __attribute__((address_space(1))) unsigned int*)g,
        (__attribute__((address_space(3))) unsigned int*)l, 16, 0, 0);
}

// ---------------------------------------------------------------------------
// prep: x,c -> bf16 row-major; Wq/Wk/Wv/Wo -> bf16 transposed [n][k].
// blocks 0..1023: xb; 1024..2047: cb; 2048..3071: W transposes (32x32 tiles).
// ---------------------------------------------------------------------------
__global__ __launch_bounds__(256) void prep(
    const float* __restrict__ x, const float* __restrict__ c,
    const float* __restrict__ Wq, const float* __restrict__ Wk,
    const float* __restrict__ Wv, const float* __restrict__ Wo,
    unsigned short* __restrict__ xb, unsigned short* __restrict__ cb,
    unsigned short* __restrict__ WT)
{
    __shared__ unsigned short tileT[32][33];
    const int bx = blockIdx.x, tid = threadIdx.x;
    if (bx < 2048) {
        const float* src = (bx < 1024) ? x : c;
        unsigned short* dst = (bx < 1024) ? xb : cb;
        const size_t base = (size_t)(bx & 1023) * 2048 + (size_t)tid * 8;
        const float4 a = *(const float4*)&src[base];
        const float4 b = *(const float4*)&src[base + 4];
        short8 o;
        o[0] = (short)f2bs(a.x); o[1] = (short)f2bs(a.y);
        o[2] = (short)f2bs(a.z); o[3] = (short)f2bs(a.w);
        o[4] = (short)f2bs(b.x); o[5] = (short)f2bs(b.y);
        o[6] = (short)f2bs(b.z); o[7] = (short)f2bs(b.w);
        *(short8*)&dst[base] = o;
    } else {
        const int r = bx - 2048;
        const int w = r >> 8, tile = r & 255;
        const int k0 = (tile >> 4) * 32, n0 = (tile & 15) * 32;
        const float* W = (w == 0) ? Wq : (w == 1) ? Wk : (w == 2) ? Wv : Wo;
        unsigned short* out = WT + (size_t)w * 512 * 512;
        const int kk = tid >> 3, ns = (tid & 7) * 4;
        const float4 v = *(const float4*)&W[(size_t)(k0 + kk) * 512 + n0 + ns];
        tileT[ns + 0][kk] = f2bs(v.x);
        tileT[ns + 1][kk] = f2bs(v.y);
        tileT[ns + 2][kk] = f2bs(v.z);
        tileT[ns + 3][kk] = f2bs(v.w);
        __syncthreads();
        const int nn = tid >> 3, ks = (tid & 7) * 4;
        ushort4 o;
        o.x = tileT[nn][ks + 0]; o.y = tileT[nn][ks + 1];
        o.z = tileT[nn][ks + 2]; o.w = tileT[nn][ks + 3];
        *(ushort4*)&out[(size_t)(n0 + nn) * 512 + k0 + ks] = o;
    }
}

// ---------------------------------------------------------------------------
// bf16 MFMA GEMM core: C[128x128] = A[128xK] * Bt[128xK]^T, K=512, BK=32.
// A,Bt row-major bf16, k-contiguous.  global_load_lds width-16 staging.
// Wave w: m-half (w&1)*64, n-half (w>>1)*64, 4x4 tiles of 16x16.
// ---------------------------------------------------------------------------
struct GemmAcc { floatx4 acc[4][4]; int mrow, kgrp, mhalf, nhalf; };

__device__ __forceinline__ void gemm_core(
    const unsigned short* __restrict__ A, const unsigned short* __restrict__ Bt,
    int m0, int n0, unsigned short* sA, unsigned short* sB, GemmAcc& g)
{
    const int tid = threadIdx.x;
    const int wave = tid >> 6, lane = tid & 63;
    g.mrow = lane & 15;
    g.kgrp = (lane >> 4) * 8;
    g.mhalf = (wave & 1) * 64;
    g.nhalf = (wave >> 1) * 64;
    const int lrow = lane >> 2;             // 0..15
    const int lseg = (lane & 3) * 16;       // byte offset in 64B row
    const int srow = wave * 32;

    #pragma unroll
    for (int i = 0; i < 4; i++)
        #pragma unroll
        for (int j = 0; j < 4; j++)
            g.acc[i][j] = (floatx4){0.f, 0.f, 0.f, 0.f};

    for (int ck = 0; ck < 16; ck++) {
        const int k0 = ck * 32;
        __syncthreads();
        #pragma unroll
        for (int j = 0; j < 2; j++) {
            const int rA = srow + j * 16 + lrow;
            gload_lds16((const char*)A + ((size_t)(m0 + rA) * 512 + k0) * 2 + lseg,
                        &sA[(size_t)(srow + j * 16) * 32]);
            gload_lds16((const char*)Bt + ((size_t)(n0 + rA) * 512 + k0) * 2 + lseg,
                        &sB[(size_t)(srow + j * 16) * 32]);
        }
        __syncthreads();
        short8 af[4], bf[4];
        #pragma unroll
        for (int i = 0; i < 4; i++)
            af[i] = *(const short8*)&sA[(size_t)(g.mhalf + i * 16 + g.mrow) * 32 + g.kgrp];
        #pragma unroll
        for (int i = 0; i < 4; i++)
            bf[i] = *(const short8*)&sB[(size_t)(g.nhalf + i * 16 + g.mrow) * 32 + g.kgrp];
        #pragma unroll
        for (int mt = 0; mt < 4; mt++)
            #pragma unroll
            for (int nt = 0; nt < 4; nt++)
                g.acc[mt][nt] = __builtin_amdgcn_mfma_f32_16x16x32_bf16(
                    af[mt], bf[nt], g.acc[mt][nt], 0, 0, 0);
    }
}

// ---------------------------------------------------------------------------
// QKV projection GEMM -> bf16 per-head compact [bh][t][64].
// ---------------------------------------------------------------------------
__global__ __launch_bounds__(256) void qkv_mfma(
    const unsigned short* __restrict__ xb, const unsigned short* __restrict__ cb,
    const unsigned short* __restrict__ WT,
    const float* __restrict__ bq, const float* __restrict__ bk,
    const float* __restrict__ bv,
    unsigned short* __restrict__ Qc, unsigned short* __restrict__ Kc,
    unsigned short* __restrict__ Vc)
{
    const int z = blockIdx.z;
    const unsigned short* A  = (z == 0) ? xb : cb;
    const unsigned short* Bt = WT + (size_t)z * 262144;
    const float* bias        = (z == 0) ? bq : (z == 1) ? bk : bv;
    unsigned short* Y        = (z == 0) ? Qc : (z == 1) ? Kc : Vc;
    const float scale        = (z == 0) ? 0.125f : 1.0f;

    __shared__ __align__(16) unsigned short sA[128 * 32];
    __shared__ __align__(16) unsigned short sB[128 * 32];

    const int m0 = blockIdx.y * 128, n0 = blockIdx.x * 128;
    GemmAcc g;
    gemm_core(A, Bt, m0, n0, sA, sB, g);

    const int lane = threadIdx.x & 63;
    const int rowq = (lane >> 4) * 4;
    #pragma unroll
    for (int nt = 0; nt < 4; nt++) {
        const int n = n0 + g.nhalf + nt * 16 + g.mrow;
        const float bv_ = bias[n];
        const int h = n >> 6, d = n & 63;
        #pragma unroll
        for (int mt = 0; mt < 4; mt++)
            #pragma unroll
            for (int r = 0; r < 4; r++) {
                const int m = m0 + g.mhalf + mt * 16 + rowq + r;
                const int bb = m >> 10, t = m & 1023;
                Y[(((size_t)bb * H_ + h) * 1024 + t) * 64 + d] =
                    f2bs((g.acc[mt][nt][r] + bv_) * scale);
            }
    }
}

// ---------------------------------------------------------------------------
// Output projection GEMM: out(fp32) = AOb(bf16) @ WoT^T + bo.
// ---------------------------------------------------------------------------
__global__ __launch_bounds__(256) void out_mfma(
    const unsigned short* __restrict__ AOb, const unsigned short* __restrict__ WoT,
    const float* __restrict__ bias, float* __restrict__ out)
{
    __shared__ __align__(16) unsigned short sA[128 * 32];
    __shared__ __align__(16) unsigned short sB[128 * 32];

    const int m0 = blockIdx.y * 128, n0 = blockIdx.x * 128;
    GemmAcc g;
    gemm_core(AOb, WoT, m0, n0, sA, sB, g);

    const int lane = threadIdx.x & 63;
    const int rowq = (lane >> 4) * 4;
    #pragma unroll
    for (int nt = 0; nt < 4; nt++) {
        const int n = n0 + g.nhalf + nt * 16 + g.mrow;
        const float bv_ = bias[n];
        #pragma unroll
        for (int mt = 0; mt < 4; mt++)
            #pragma unroll
            for (int r = 0; r < 4; r++) {
                const int m = m0 + g.mhalf + mt * 16 + rowq + r;
                out[(size_t)m * 512 + n] = g.acc[mt][nt][r] + bv_;
            }
    }
}

// ---------------------------------------------------------------------------
// MFMA flash attention (unchanged from R3 except bf16 output).
// ---------------------------------------------------------------------------
__global__ __launch_bounds__(256) void attn_mfma(
    const unsigned short* __restrict__ Qc, const unsigned short* __restrict__ Kc,
    const unsigned short* __restrict__ Vc,
    const float* __restrict__ rk, const float* __restrict__ rv,
    unsigned short* __restrict__ AOb)
{
    __shared__ float qbL[64 * 9];
    __shared__ float bandL[64 * 9];
    __shared__ float rvL[9 * 64];
    __shared__ __align__(16) unsigned short VtL[64 * 72];
    __shared__ __align__(16) float PL[4][16 * 68];

    const int tb = blockIdx.x, h = blockIdx.y, b = blockIdx.z;
    const int bh = b * H_ + h;
    const int tid = threadIdx.x;
    const int wave = tid >> 6, lane = tid & 63;
    const int t0 = tb * 64;
    const int t0w = t0 + wave * 16;
    const size_t qkbase = (size_t)bh * T_ * 64;

    for (int idx = tid; idx < 576; idx += 256) {
        bandL[idx] = -1e30f;
        rvL[idx] = rv[idx];
        const int row = idx / 9, w = idx - row * 9;
        const unsigned short* qp = &Qc[qkbase + (size_t)(t0 + row) * 64];
        float s = 0.f;
        for (int d = 0; d < 64; d++) s = fmaf(bs2f(qp[d]), rk[w * 64 + d], s);
        qbL[idx] = s;
    }

    const int mrow = lane & 15;
    const int kgrp = (lane >> 4) * 8;

    const short8 aQ0 = *(const short8*)&Qc[qkbase + (size_t)(t0w + mrow) * 64 + kgrp];
    const short8 aQ1 = *(const short8*)&Qc[qkbase + (size_t)(t0w + mrow) * 64 + 32 + kgrp];

    floatx4 Oc[4];
    float mrun[4], lrun[4];
    #pragma unroll
    for (int r = 0; r < 4; r++) { mrun[r] = -1e30f; lrun[r] = 0.f; }
    #pragma unroll
    for (int dt = 0; dt < 4; dt++) Oc[dt] = (floatx4){0.f, 0.f, 0.f, 0.f};

    float* Pw = &PL[wave][0];
    float* qbw = &qbL[wave * 16 * 9];
    float* bandw = &bandL[wave * 16 * 9];

    for (int ck = 0; ck < 16; ck++) {
        const int s0 = ck * 64;
        __syncthreads();
        {
            const int srow = tid >> 3;
            const int dbase = (tid & 7) * 8;
            #pragma unroll
            for (int pass = 0; pass < 2; pass++) {
                const int s = pass * 32 + srow;
                const short8 vv = *(const short8*)&Vc[qkbase + (size_t)(s0 + s) * 64 + dbase];
                #pragma unroll
                for (int i = 0; i < 8; i++)
                    VtL[(dbase + i) * 72 + s] = (unsigned short)vv[i];
            }
        }
        __syncthreads();

        floatx4 Sc[4];
        #pragma unroll
        for (int st = 0; st < 4; st++) {
            const size_t krow = qkbase + (size_t)(s0 + st * 16 + mrow) * 64;
            const short8 bK0 = *(const short8*)&Kc[krow + kgrp];
            const short8 bK1 = *(const short8*)&Kc[krow + 32 + kgrp];
            floatx4 s4 = {0.f, 0.f, 0.f, 0.f};
            s4 = __builtin_amdgcn_mfma_f32_16x16x32_bf16(aQ0, bK0, s4, 0, 0, 0);
            s4 = __builtin_amdgcn_mfma_f32_16x16x32_bf16(aQ1, bK1, s4, 0, 0, 0);
            Sc[st] = s4;
        }

        #pragma unroll
        for (int st = 0; st < 4; st++) {
            #pragma unroll
            for (int r = 0; r < 4; r++) {
                const int tloc = (lane >> 4) * 4 + r;
                const int rel = (s0 + st * 16 + mrow) - (t0w + tloc);
                if (rel >= -4 && rel <= 4) {
                    const float sc = Sc[st][r] + qbw[tloc * 9 + rel + 4];
                    Sc[st][r] = sc;
                    bandw[tloc * 9 + rel + 4] = sc;
                }
            }
        }

        float resc[4], ls[4];
        #pragma unroll
        for (int r = 0; r < 4; r++) {
            float mc = fmaxf(fmaxf(Sc[0][r], Sc[1][r]), fmaxf(Sc[2][r], Sc[3][r]));
            #pragma unroll
            for (int mk = 1; mk < 16; mk <<= 1)
                mc = fmaxf(mc, __shfl_xor(mc, mk));
            const float mnew = fmaxf(mrun[r], mc);
            resc[r] = __expf(mrun[r] - mnew);
            mrun[r] = mnew;
            ls[r] = 0.f;
        }
        #pragma unroll
        for (int st = 0; st < 4; st++) {
            #pragma unroll
            for (int r = 0; r < 4; r++) {
                const int tloc = (lane >> 4) * 4 + r;
                const float p = __expf(Sc[st][r] - mrun[r]);
                Pw[tloc * 68 + st * 16 + mrow] = p;
                ls[r] += p;
            }
        }
        #pragma unroll
        for (int r = 0; r < 4; r++) {
            float v = ls[r];
            #pragma unroll
            for (int mk = 1; mk < 16; mk <<= 1)
                v += __shfl_xor(v, mk);
            lrun[r] = lrun[r] * resc[r] + v;
        }
        #pragma unroll
        for (int dt = 0; dt < 4; dt++)
            #pragma unroll
            for (int r = 0; r < 4; r++)
                Oc[dt][r] *= resc[r];

        #pragma unroll
        for (int c = 0; c < 2; c++) {
            const float4 p0 = *(const float4*)&Pw[mrow * 68 + c * 32 + kgrp];
            const float4 p1 = *(const float4*)&Pw[mrow * 68 + c * 32 + kgrp + 4];
            short8 aP;
            aP[0] = (short)f2bs(p0.x); aP[1] = (short)f2bs(p0.y);
            aP[2] = (short)f2bs(p0.z); aP[3] = (short)f2bs(p0.w);
            aP[4] = (short)f2bs(p1.x); aP[5] = (short)f2bs(p1.y);
            aP[6] = (short)f2bs(p1.z); aP[7] = (short)f2bs(p1.w);
            #pragma unroll
            for (int dt = 0; dt < 4; dt++) {
                const short8 bV = *(const short8*)&VtL[(dt * 16 + mrow) * 72 + c * 32 + kgrp];
                Oc[dt] = __builtin_amdgcn_mfma_f32_16x16x32_bf16(aP, bV, Oc[dt], 0, 0, 0);
            }
        }
    }

    float invl[4];
    #pragma unroll
    for (int r = 0; r < 4; r++) invl[r] = 1.f / lrun[r];
    #pragma unroll
    for (int dt = 0; dt < 4; dt++)
        #pragma unroll
        for (int r = 0; r < 4; r++)
            Oc[dt][r] *= invl[r];

    for (int w = 0; w < 9; w++) {
        float pw[4];
        #pragma unroll
        for (int r = 0; r < 4; r++) {
            const int tloc = (lane >> 4) * 4 + r;
            pw[r] = __expf(bandw[tloc * 9 + w] - mrun[r]) * invl[r];
        }
        #pragma unroll
        for (int dt = 0; dt < 4; dt++) {
            const float rvv = rvL[w * 64 + dt * 16 + mrow];
            #pragma unroll
            for (int r = 0; r < 4; r++)
                Oc[dt][r] = fmaf(pw[r], rvv, Oc[dt][r]);
        }
    }

    const size_t aobase = ((size_t)b * T_) * C_ + (size_t)h * 64;
    #pragma unroll
    for (int dt = 0; dt < 4; dt++)
        #pragma unroll
        for (int r = 0; r < 4; r++) {
            const int t = t0w + (lane >> 4) * 4 + r;
            AOb[aobase + (size_t)t * C_ + dt * 16 + mrow] = f2bs(Oc[dt][r]);
        }
}

// ---------------------------------------------------------------------------
extern "C" void kernel_launch(void* const* d_in, const int* in_sizes, int n_in,
                              void* d_out, int out_size, void* d_ws, size_t ws_size,
                              hipStream_t stream)
{
    const float* x  = (const float*)d_in[0];
    const float* c  = (const float*)d_in[1];
    const float* Wq = (const float*)d_in[2];
    const float* bq = (const float*)d_in[3];
    const float* Wk = (const float*)d_in[4];
    const float* bk = (const float*)d_in[5];
    const float* Wv = (const float*)d_in[6];
    const float* bv = (const float*)d_in[7];
    const float* Wo = (const float*)d_in[8];
    const float* bo = (const float*)d_in[9];
    const float* rk = (const float*)d_in[10];
    const float* rv = (const float*)d_in[11];

    unsigned short* xb = (unsigned short*)d_ws;            // [4096][512] bf16
    unsigned short* cb  = xb + (size_t)4096 * 512;
    unsigned short* WT  = cb + (size_t)4096 * 512;         // 4x [512n][512k] bf16
    unsigned short* Qc  = WT + (size_t)4 * 512 * 512;      // [32][1024][64] bf16
    unsigned short* Kc  = Qc + (size_t)32 * 1024 * 64;
    unsigned short* Vc  = Kc + (size_t)32 * 1024 * 64;
    unsigned short* AOb = Vc + (size_t)32 * 1024 * 64;     // [4096][512] bf16

    prep<<<3072, 256, 0, stream>>>(x, c, Wq, Wk, Wv, Wo, xb, cb, WT);
    qkv_mfma<<<dim3(4, 32, 3), 256, 0, stream>>>(xb, cb, WT, bq, bk, bv, Qc, Kc, Vc);
    attn_mfma<<<dim3(16, 8, 4), 256, 0, stream>>>(Qc, Kc, Vc, rk, rv, AOb);
    out_mfma<<<dim3(4, 32), 256, 0, stream>>>(AOb, WT + (size_t)3 * 262144, bo, (float*)d_out);
}